// Round 17
// baseline (1689.728 us; speedup 1.0000x reference)
//
#include <hip/hip_runtime.h>
#include <math.h>

#define BATCH 32768
#define NVARS 50
#define H1 1024
#define H2 1024
#define H3 256
#define NOUT 100
#define EPSBN 1e-5f

#define TF   0.05f
#define AF   20.0f
#define JF   400.0f
#define VMAX 1.0f
#define AMAX 2.0f
#define JMAX 5.0f
#define PMAX 3.14159265358979323846f

typedef unsigned short ushort_t;
typedef __attribute__((ext_vector_type(8))) short short8;
typedef __attribute__((ext_vector_type(4))) float f32x4;

// ---------------------------------------------------------------------------
// Device-global scratch (no ws_size dependence).
// ---------------------------------------------------------------------------
__device__ float g_z1[(size_t)BATCH * H1];   // z1 / (z3, nno reuse)
__device__ float g_z2[(size_t)BATCH * H2];
__device__ float g_xpad[(size_t)BATCH * 64]; // x zero-padded K=50 -> 64
__device__ float g_ps[32 * 1024];
__device__ float g_pq[32 * 1024];
__device__ float g_scale[3 * 1024];
__device__ float g_shift[3 * 1024];
__device__ float g_Mp[2800];                 // Qinv packed [k][par][28] (pad 0)
__device__ float g_xT[(size_t)NVARS * BATCH];
__device__ float g_nnT[(size_t)NOUT * BATCH];
__device__ ushort_t g_w1p[(size_t)3 * 64 * H1];   // packed W1 (K padded to 64)
__device__ ushort_t g_w2p[(size_t)3 * H1 * H2];   // packed fragment-order tiers
__device__ ushort_t g_w3p[(size_t)3 * H2 * H3];

// ---------------------------------------------------------------------------
// float -> bf16 triple split (RNE), f ~= hi + mid + lo with rel err ~2^-26.
// ---------------------------------------------------------------------------
__device__ __forceinline__ void split3(float f, ushort_t& h, ushort_t& m, ushort_t& l)
{
    unsigned u = __float_as_uint(f);
    unsigned r = u + 0x7fffu + ((u >> 16) & 1u);
    h = (ushort_t)(r >> 16);
    float f1 = f - __uint_as_float((unsigned)h << 16);
    unsigned u1 = __float_as_uint(f1);
    unsigned r1 = u1 + 0x7fffu + ((u1 >> 16) & 1u);
    m = (ushort_t)(r1 >> 16);
    float f2 = f1 - __uint_as_float((unsigned)m << 16);
    unsigned u2 = __float_as_uint(f2);
    unsigned r2 = u2 + 0x7fffu + ((u2 >> 16) & 1u);
    l = (ushort_t)(r2 >> 16);
}

// ---------------------------------------------------------------------------
// Build Mp[(k*2+par)*28 + jj] = Q_inv[par*25+jj][k] (jj<25; pad 0) via f64
// Gauss-Jordan with partial pivoting (bitwise-identical values).
// ---------------------------------------------------------------------------
__global__ void build_M(float* __restrict__ Mout)
{
    __shared__ double aug[52][104];
    __shared__ int piv;
    int tid = threadIdx.x;

    const double Tf = (double)0.05f;
    const double c3[3] = { 400.0, -800.0, 400.0 };

    for (int idx = tid; idx < 52 * 104; idx += 64) {
        int j = idx / 104, k = idx % 104;
        double v = 0.0;
        if (k >= 52) {
            v = (k == 52 + j) ? 1.0 : 0.0;
        } else if (j < 50 && k < 50) {
            double q = (j == k) ? 3.0 : 0.0;
            if (j == k) q += 800.0 * ((j < 49 ? 1 : 0) + (j > 0 ? 1 : 0));
            if (j - k == 1 || k - j == 1) q += -800.0;
            int lo = j > k ? j : k; lo -= 2; if (lo < 0) lo = 0;
            int hi = j < k ? j : k; if (hi > 47) hi = 47;
            for (int i = lo; i <= hi; ++i) {
                int dj = j - i, dk = k - i;
                if (dj >= 0 && dj <= 2 && dk >= 0 && dk <= 2)
                    q += 2.0 * c3[dj] * c3[dk];
            }
            int mx = j > k ? j : k;
            q += 2.0 * Tf * Tf * (double)(50 - mx);
            v = q;
        } else if ((j == 50 && k == 0) || (j == 0 && k == 50) ||
                   (j == 51 && k == 49) || (j == 49 && k == 51)) {
            v = 1.0;
        }
        aug[j][k] = v;
    }
    __syncthreads();

    for (int c = 0; c < 52; ++c) {
        if (tid == 0) {
            int p = c; double best = fabs(aug[c][c]);
            for (int r = c + 1; r < 52; ++r) {
                double v = fabs(aug[r][c]);
                if (v > best) { best = v; p = r; }
            }
            piv = p;
        }
        __syncthreads();
        int p = piv;
        if (p != c) {
            for (int k = tid; k < 104; k += 64) {
                double t = aug[c][k]; aug[c][k] = aug[p][k]; aug[p][k] = t;
            }
        }
        __syncthreads();
        double pv = aug[c][c];
        __syncthreads();
        for (int k = tid; k < 104; k += 64) aug[c][k] /= pv;
        __syncthreads();
        if (tid < 52 && tid != c) {
            double f = aug[tid][c];
            for (int k = 0; k < 104; ++k) aug[tid][k] -= f * aug[c][k];
        }
        __syncthreads();
    }

    // Mp[(k*2+par)*28 + slot] = Qinv[par*25+slot][k]  (slot 25..27 -> 0)
    for (int idx = tid; idx < 2800; idx += 64) {
        int slot = idx % 28;
        int kk2 = idx / 28;
        int k = kk2 >> 1, par = kk2 & 1;
        int j = par * 25 + slot;
        Mout[idx] = (slot < 25) ? (float)aug[j][52 + k] : 0.f;
    }
}

// ---------------------------------------------------------------------------
// Pad x[BATCH][50] -> xpad[BATCH][64] (zeros beyond col 50).
// ---------------------------------------------------------------------------
__global__ __launch_bounds__(256)
void xpad_k(const float* __restrict__ X, float* __restrict__ XP)
{
    size_t idx = (size_t)blockIdx.x * 256 + threadIdx.x;
    size_t total = (size_t)BATCH * 64;
    for (; idx < total; idx += (size_t)gridDim.x * 256) {
        int col = (int)(idx & 63);
        size_t row = idx >> 6;
        XP[idx] = (col < NVARS) ? X[row * NVARS + col] : 0.f;
    }
}

// ---------------------------------------------------------------------------
// Transpose Z[BATCH][C] -> ZT[C][BATCH], 64 rows per block.
// ---------------------------------------------------------------------------
template <int C>
__global__ __launch_bounds__(64)
void transp(const float* __restrict__ Z, float* __restrict__ ZT)
{
    __shared__ float t[64][C + 1];
    const int lane = threadIdx.x;
    const size_t r0 = (size_t)blockIdx.x * 64;
#pragma unroll 1
    for (int i = 0; i < C; ++i) {
        int idx = i * 64 + lane;
        int r = idx / C, c = idx % C;
        t[r][c] = Z[r0 * C + idx];
    }
    __syncthreads();
#pragma unroll 1
    for (int c = 0; c < C; ++c)
        ZT[(size_t)c * BATCH + r0 + lane] = t[lane][c];
}

// ---------------------------------------------------------------------------
// Triple-split W[Kr][N] f32 -> Wp packed in MFMA-fragment order, K padded
// to multiple of 32 (rows >= Kr are zeros).
// ---------------------------------------------------------------------------
__global__ __launch_bounds__(512)
void wsplit_pack(const float* __restrict__ W, ushort_t* __restrict__ Wp,
                 int K, int N, int Kr)
{
    int t = threadIdx.x;
    int n0 = blockIdx.x * 16, k0 = blockIdx.y * 32;
    int kk = t >> 4, nn = t & 15;
    float f = (k0 + kk < Kr) ? W[(size_t)(k0 + kk) * N + n0 + nn] : 0.f;
    ushort_t h, m, l;
    split3(f, h, m, l);
    int Nsub = N >> 4;
    int lane = (kk >> 3) * 16 + nn, e = kk & 7;
    size_t base = ((size_t)((k0 >> 5) * Nsub + (n0 >> 4)) * 3) * 512 + lane * 8 + e;
    Wp[base]        = h;
    Wp[base + 512]  = m;
    Wp[base + 1024] = l;
}

// ---------------------------------------------------------------------------
// MFMA GEMM (pipelined, R17): BM=64, BN=256, 256 thr (4 waves), dbuf 24KB
// LDS (A only, uint4 staging = conflict-free), one barrier/K-step, early A
// prefetch, packed-global W with REGISTER DOUBLE-BUFFERED W PREFETCH: W
// frags for step ks+1 load before step ks's MFMA block (2-step unrolled
// loop, named register sets) -> W L2 latency hides under 96 MFMAs.
// Requires nk even (K % 64 == 0). FP order identical to R15.
// ---------------------------------------------------------------------------
template <int BN_APPLY>
__global__ __launch_bounds__(256)
void gemm_mfma(const float* __restrict__ A, const ushort_t* __restrict__ Wp,
               const float* __restrict__ bias,
               const float* __restrict__ scale, const float* __restrict__ shift,
               float* __restrict__ C, int M, int K, int N, int ntn)
{
    __shared__ __attribute__((aligned(16))) ushort_t lds[2][3][4][64][8];  // 24 KB

    const int nwg = gridDim.x;
    const int chunk = nwg >> 3;
    const int b = blockIdx.x;
    const int logical = (b & 7) * chunk + (b >> 3);
    const int rowt = logical / ntn;
    const int colt = logical - rowt * ntn;
    const int row0 = rowt * 64;
    const int col0s = colt * 16;

    const int t = threadIdx.x;
    const int lane = t & 63, wn = t >> 6;
    const int fr = lane & 15, fg = lane >> 4;
    const int srow = t & 63, skc = t >> 6;
    const int Nsub = N >> 4;
    const int nk = K >> 5;

    f32x4 acc[4][4];
#pragma unroll
    for (int m = 0; m < 4; ++m)
#pragma unroll
        for (int n = 0; n < 4; ++n)
#pragma unroll
            for (int q = 0; q < 4; ++q) acc[m][n][q] = 0.f;

    const float* arow = A + (size_t)(row0 + srow) * K + skc * 8;
    float4 pf0, pf1;
    short8 bh0[4], bm0[4], bl0[4], bh1[4], bm1[4], bl1[4];

#define PKU(a,b2) (((unsigned)(a)) | (((unsigned)(b2)) << 16))
#define LOADPF(KS)                                                             \
    {                                                                          \
        pf0 = *(const float4*)(arow + (KS) * 32);                              \
        pf1 = *(const float4*)(arow + (KS) * 32 + 4);                          \
    }
#define LOADW(BH, BMM, BL, KS)                                                 \
    {                                                                          \
        _Pragma("unroll")                                                      \
        for (int n = 0; n < 4; ++n) {                                          \
            size_t base = ((size_t)((KS) * Nsub + col0s + wn * 4 + n) * 3) * 512 + lane * 8; \
            BH[n]  = *(const short8*)(Wp + base);                              \
            BMM[n] = *(const short8*)(Wp + base + 512);                        \
            BL[n]  = *(const short8*)(Wp + base + 1024);                       \
        }                                                                      \
    }
#define STAGEW(BUF, KOFF)                                                      \
    {                                                                          \
        float v[8];                                                            \
        v[0] = pf0.x; v[1] = pf0.y; v[2] = pf0.z; v[3] = pf0.w;                \
        v[4] = pf1.x; v[5] = pf1.y; v[6] = pf1.z; v[7] = pf1.w;                \
        if (BN_APPLY) {                                                        \
            const float* scp = scale + (KOFF) + skc * 8;                       \
            const float* shp = shift + (KOFF) + skc * 8;                       \
            float4 sc0 = *(const float4*)scp, sc1 = *(const float4*)(scp + 4); \
            float4 sh0 = *(const float4*)shp, sh1 = *(const float4*)(shp + 4); \
            v[0] = fmaxf(v[0] * sc0.x + sh0.x, 0.f);                           \
            v[1] = fmaxf(v[1] * sc0.y + sh0.y, 0.f);                           \
            v[2] = fmaxf(v[2] * sc0.z + sh0.z, 0.f);                           \
            v[3] = fmaxf(v[3] * sc0.w + sh0.w, 0.f);                           \
            v[4] = fmaxf(v[4] * sc1.x + sh1.x, 0.f);                           \
            v[5] = fmaxf(v[5] * sc1.y + sh1.y, 0.f);                           \
            v[6] = fmaxf(v[6] * sc1.z + sh1.z, 0.f);                           \
            v[7] = fmaxf(v[7] * sc1.w + sh1.w, 0.f);                           \
        }                                                                      \
        ushort_t h_[8], m_[8], l_[8];                                          \
        _Pragma("unroll")                                                      \
        for (int q = 0; q < 8; ++q) split3(v[q], h_[q], m_[q], l_[q]);         \
        *(uint4*)&lds[BUF][0][skc][srow][0] = make_uint4(                      \
            PKU(h_[0],h_[1]), PKU(h_[2],h_[3]), PKU(h_[4],h_[5]), PKU(h_[6],h_[7])); \
        *(uint4*)&lds[BUF][1][skc][srow][0] = make_uint4(                      \
            PKU(m_[0],m_[1]), PKU(m_[2],m_[3]), PKU(m_[4],m_[5]), PKU(m_[6],m_[7])); \
        *(uint4*)&lds[BUF][2][skc][srow][0] = make_uint4(                      \
            PKU(l_[0],l_[1]), PKU(l_[2],l_[3]), PKU(l_[4],l_[5]), PKU(l_[6],l_[7])); \
    }
#define MFMABLK(BH, BMM, BL, CUR)                                              \
    {                                                                          \
        _Pragma("unroll")                                                      \
        for (int m = 0; m < 4; ++m) {                                          \
            int rr_ = m * 16 + fr;                                             \
            short8 a_h = *(const short8*)&lds[CUR][0][fg][rr_][0];             \
            short8 a_m = *(const short8*)&lds[CUR][1][fg][rr_][0];             \
            short8 a_l = *(const short8*)&lds[CUR][2][fg][rr_][0];             \
            _Pragma("unroll")                                                  \
            for (int n = 0; n < 4; ++n) {                                      \
                f32x4 c = acc[m][n];                                           \
                c = __builtin_amdgcn_mfma_f32_16x16x32_bf16(a_l, BH[n],  c, 0, 0, 0); \
                c = __builtin_amdgcn_mfma_f32_16x16x32_bf16(a_h, BL[n],  c, 0, 0, 0); \
                c = __builtin_amdgcn_mfma_f32_16x16x32_bf16(a_m, BMM[n], c, 0, 0, 0); \
                c = __builtin_amdgcn_mfma_f32_16x16x32_bf16(a_m, BH[n],  c, 0, 0, 0); \
                c = __builtin_amdgcn_mfma_f32_16x16x32_bf16(a_h, BMM[n], c, 0, 0, 0); \
                c = __builtin_amdgcn_mfma_f32_16x16x32_bf16(a_h, BH[n],  c, 0, 0, 0); \
                acc[m][n] = c;                                                 \
            }                                                                  \
        }                                                                      \
    }

    // prologue: stage tile 0, load W set 0
    LOADPF(0)
    STAGEW(0, 0)
    LOADW(bh0, bm0, bl0, 0)
    __syncthreads();

    int cur = 0;
    for (int ks = 0; ks < nk; ks += 2) {
        // even step (ks): consumes W set 0; prefetch A tile ks+1 + W set 1
        LOADPF(ks + 1)
        LOADW(bh1, bm1, bl1, ks + 1)
        MFMABLK(bh0, bm0, bl0, cur)
        STAGEW(cur ^ 1, (ks + 1) * 32)
        __syncthreads();
        cur ^= 1;
        // odd step (ks+1): consumes W set 1; prefetch A tile ks+2 + W set 0
        if (ks + 2 < nk) {
            LOADPF(ks + 2)
            LOADW(bh0, bm0, bl0, ks + 2)
        }
        MFMABLK(bh1, bm1, bl1, cur)
        if (ks + 2 < nk) {
            STAGEW(cur ^ 1, (ks + 2) * 32)
        }
        __syncthreads();
        cur ^= 1;
    }
#undef MFMABLK
#undef STAGEW
#undef LOADW
#undef LOADPF
#undef PKU

#pragma unroll
    for (int m = 0; m < 4; ++m)
#pragma unroll
        for (int n = 0; n < 4; ++n) {
            int cc = (col0s + wn * 4 + n) * 16 + fr;
            float bv = bias[cc];
#pragma unroll
            for (int q = 0; q < 4; ++q) {
                int rr = row0 + m * 16 + fg * 4 + q;
                C[(size_t)rr * N + cc] = acc[m][n][q] + bv;
            }
        }
}

// ---------------------------------------------------------------------------
// fp32 tiled GEMM (GEMM4 N=100 only).
// ---------------------------------------------------------------------------
template <int BN_APPLY>
__global__ __launch_bounds__(256)
void gemm_k(const float* __restrict__ A, const float* __restrict__ W,
            const float* __restrict__ bias,
            const float* __restrict__ scale, const float* __restrict__ shift,
            float* __restrict__ C, int M, int K, int N)
{
    const int BM = 128, BN = 128, BK = 16;
    __shared__ __attribute__((aligned(16))) float As[BK][BM + 4];
    __shared__ __attribute__((aligned(16))) float Ws[BK][BN];
    int tid = threadIdx.x;
    int tm = tid >> 4, tn = tid & 15;
    int row0 = blockIdx.x * BM, col0 = blockIdx.y * BN;

    float acc[8][8];
#pragma unroll
    for (int i = 0; i < 8; ++i)
#pragma unroll
        for (int j = 0; j < 8; ++j) acc[i][j] = 0.f;

    int alr = tid >> 4;
    int alk = tid & 15;
    int wlc = tid & 127;
    int wlk = tid >> 7;

    for (int k0 = 0; k0 < K; k0 += BK) {
#pragma unroll
        for (int i = 0; i < 8; ++i) {
            int rr = row0 + alr + i * 16;
            int kk = k0 + alk;
            float v = 0.f;
            if (kk < K) {
                v = A[(size_t)rr * K + kk];
                if (BN_APPLY) v = fmaxf(v * scale[kk] + shift[kk], 0.f);
            }
            As[alk][alr + i * 16] = v;
        }
#pragma unroll
        for (int i = 0; i < 8; ++i) {
            int kk = k0 + wlk + i * 2;
            int cc = col0 + wlc;
            Ws[wlk + i * 2][wlc] = (kk < K && cc < N) ? W[(size_t)kk * N + cc] : 0.f;
        }
        __syncthreads();
#pragma unroll
        for (int kk = 0; kk < BK; ++kk) {
            float av[8], wv[8];
            float4 tv;
            tv = *(const float4*)&As[kk][tm * 8];     av[0]=tv.x; av[1]=tv.y; av[2]=tv.z; av[3]=tv.w;
            tv = *(const float4*)&As[kk][tm * 8 + 4]; av[4]=tv.x; av[5]=tv.y; av[6]=tv.z; av[7]=tv.w;
            tv = *(const float4*)&Ws[kk][tn * 8];     wv[0]=tv.x; wv[1]=tv.y; wv[2]=tv.z; wv[3]=tv.w;
            tv = *(const float4*)&Ws[kk][tn * 8 + 4]; wv[4]=tv.x; wv[5]=tv.y; wv[6]=tv.z; wv[7]=tv.w;
#pragma unroll
            for (int i = 0; i < 8; ++i)
#pragma unroll
                for (int j = 0; j < 8; ++j) acc[i][j] += av[i] * wv[j];
        }
        __syncthreads();
    }
#pragma unroll
    for (int i = 0; i < 8; ++i) {
        int rr = row0 + tm * 8 + i;
#pragma unroll
        for (int j = 0; j < 8; ++j) {
            int cc = col0 + tn * 8 + j;
            if (cc < N) C[(size_t)rr * N + cc] = acc[i][j] + bias[cc];
        }
    }
}

// ---------------------------------------------------------------------------
// BatchNorm stats.
// ---------------------------------------------------------------------------
__global__ __launch_bounds__(256)
void stats_part(const float* __restrict__ Z, float* __restrict__ ps,
                float* __restrict__ pq, int M, int C, int chunks)
{
    int lc = threadIdx.x & 63;
    int col = blockIdx.x * 64 + lc;
    int rg = threadIdx.x >> 6;
    int rpc = M / chunks;
    int r0 = blockIdx.y * rpc;
    float s = 0.f, q = 0.f;
    for (int rr = r0 + rg; rr < r0 + rpc; rr += 4) {
        float v = Z[(size_t)rr * C + col];
        s += v; q += v * v;
    }
    __shared__ float ls[4][64], lq[4][64];
    ls[rg][lc] = s; lq[rg][lc] = q;
    __syncthreads();
    if (rg == 0) {
        float S = ls[0][lc] + ls[1][lc] + ls[2][lc] + ls[3][lc];
        float Q = lq[0][lc] + lq[1][lc] + lq[2][lc] + lq[3][lc];
        ps[(size_t)blockIdx.y * C + col] = S;
        pq[(size_t)blockIdx.y * C + col] = Q;
    }
}

__global__ void stats_fin(const float* __restrict__ ps, const float* __restrict__ pq,
                          const float* __restrict__ g, const float* __restrict__ be,
                          float* __restrict__ scale, float* __restrict__ shift,
                          int C, int M, int chunks)
{
    int c = blockIdx.x * blockDim.x + threadIdx.x;
    if (c >= C) return;
    float S = 0.f, Q = 0.f;
    for (int i = 0; i < chunks; ++i) { S += ps[(size_t)i * C + c]; Q += pq[(size_t)i * C + c]; }
    float inv = 1.0f / (float)M;
    float mean = S * inv;
    float var = Q * inv - mean * mean;
    float rstd = 1.0f / sqrtf(var + EPSBN);
    float sc = g[c] * rstd;
    scale[c] = sc;
    shift[c] = be[c] - mean * sc;
}

// ---------------------------------------------------------------------------
// Fused 15-iteration ADMM, 2 lanes/row (R14 structure, unchanged — grid-
// capped at 1 wave/SIMD; known-good at ~370 us, VGPR 92, no spill).
// ---------------------------------------------------------------------------
__global__ __launch_bounds__(64, 1)
void iter_k(const float* __restrict__ XT, const float* __restrict__ NNT,
            const float* __restrict__ Mp, float* __restrict__ out)
{
    __shared__ float sA[50 * 32];
    __shared__ float sB[50 * 32];
    __shared__ float sLam[50 * 32];
    __shared__ float sRh[50 * 32];
    const int lane = threadIdx.x;
    const int r = lane >> 1, par = lane & 1;
    const int base = blockIdx.x * 32;
    const int row = base + r;
#define IDX2(k) (((k) << 5) + r)

#pragma unroll 1
    for (int idx = lane; idx < 1600; idx += 64) {
        int k = idx >> 5, rr = idx & 31;
        sA[idx]   = NNT[(size_t)k * BATCH + base + rr];
        sLam[idx] = NNT[(size_t)(50 + k) * BATCH + base + rr];
    }
    float* cx = sA;
    float* cn = sB;
    float fps = 0.f, prs = 0.f;
    float rh[50];
    const float* mp = Mp + par * 28;

#pragma unroll 1
    for (int it = 0; it < 15; ++it) {
        // ---- pass 1: rh = A^T min(b, A xi); xi via sliding LDS reads
#pragma unroll
        for (int k = 0; k < 50; ++k) rh[k] = 0.f;
        {
            float pre = 0.f, Sp = 0.f, ap = 0.f;
            float xc = cx[IDX2(0)];
#pragma unroll
            for (int k = 0; k < 50; ++k) {
                float xn = (k < 49) ? cx[IDX2(k + 1)] : 0.f;
                rh[k] += fminf(VMAX, xc) - fminf(VMAX, -xc);
                rh[k] -= TF * Sp;
                pre += xc;
                float p = TF * pre;
                Sp += fminf(PMAX, p) - fminf(PMAX, -p);
                if (k < 49) {
                    float a = AF * (xn - xc);
                    float da = fminf(AMAX, a) - fminf(AMAX, -a);
                    rh[k] -= AF * da; rh[k + 1] += AF * da;
                    if (k >= 1) {
                        float j = AF * (a - ap);
                        float dj = fminf(JMAX, j) - fminf(JMAX, -j);
                        rh[k - 1] += JF * dj; rh[k] -= 2.f * JF * dj; rh[k + 1] += JF * dj;
                    }
                    ap = a;
                }
                xc = xn;
            }
            float Stot = TF * Sp;
            // combine: + lam (LDS) + x (global, L2-resident) + Stot -> sRh
#pragma unroll
            for (int k = 0; k < 50; ++k)
                sRh[IDX2(k)] = rh[k] + sLam[IDX2(k)] + XT[(size_t)k * BATCH + row] + Stot;
        }

        // ---- matvec half: xin[par*25+jj] = sum_k Mp[(2k+par)*28+jj]*sRh[k]
        {
            float xr[28];
#pragma unroll
            for (int jj = 0; jj < 28; ++jj) xr[jj] = 0.f;
#pragma unroll 2
            for (int k = 0; k < 50; ++k) {
                float rv = sRh[IDX2(k)];
                const float4* m4 = (const float4*)(mp + k * 56);
#pragma unroll
                for (int p4 = 0; p4 < 7; ++p4) {
                    float4 mv = m4[p4];
                    xr[p4 * 4 + 0] += mv.x * rv;
                    xr[p4 * 4 + 1] += mv.y * rv;
                    xr[p4 * 4 + 2] += mv.z * rv;
                    xr[p4 * 4 + 3] += mv.w * rv;
                }
            }
#pragma unroll
            for (int jj = 0; jj < 25; ++jj)
                cn[((par * 25 + jj) << 5) + r] = xr[jj];
        }

        // ---- pass 2: residual/s norms + g (into rh); duplicated per pair
        float res2 = 0.f, ds2 = 0.f, dxi2 = 0.f, dlam2 = 0.f;
#pragma unroll
        for (int k = 0; k < 50; ++k) rh[k] = 0.f;
        {
            float preo = 0.f, pren = 0.f, SpF = 0.f, aop = 0.f, anp = 0.f;
            float xoc = cx[IDX2(0)], xnc = cn[IDX2(0)];
#pragma unroll
            for (int k = 0; k < 50; ++k) {
                float xon = (k < 49) ? cx[IDX2(k + 1)] : 0.f;
                float xnn = (k < 49) ? cn[IDX2(k + 1)] : 0.f;
                float d = xoc - xnc; dxi2 += d * d;
                float rp = fmaxf(xnc - VMAX, 0.f), rm = fmaxf(-xnc - VMAX, 0.f);
                res2 += rp * rp + rm * rm;
                float so = fmaxf(VMAX - xoc, 0.f), sn = fmaxf(VMAX - xnc, 0.f);
                d = so - sn; ds2 += d * d;
                so = fmaxf(VMAX + xoc, 0.f); sn = fmaxf(VMAX + xnc, 0.f);
                d = so - sn; ds2 += d * d;
                rh[k] += rp - rm;
                rh[k] -= TF * SpF;
                preo += xoc; pren += xnc;
                float po = TF * preo, pn = TF * pren;
                rp = fmaxf(pn - PMAX, 0.f); rm = fmaxf(-pn - PMAX, 0.f);
                res2 += rp * rp + rm * rm;
                so = fmaxf(PMAX - po, 0.f); sn = fmaxf(PMAX - pn, 0.f);
                d = so - sn; ds2 += d * d;
                so = fmaxf(PMAX + po, 0.f); sn = fmaxf(PMAX + pn, 0.f);
                d = so - sn; ds2 += d * d;
                SpF += rp - rm;
                if (k < 49) {
                    float ao = AF * (xon - xoc), an = AF * (xnn - xnc);
                    rp = fmaxf(an - AMAX, 0.f); rm = fmaxf(-an - AMAX, 0.f);
                    res2 += rp * rp + rm * rm;
                    so = fmaxf(AMAX - ao, 0.f); sn = fmaxf(AMAX - an, 0.f);
                    d = so - sn; ds2 += d * d;
                    so = fmaxf(AMAX + ao, 0.f); sn = fmaxf(AMAX + an, 0.f);
                    d = so - sn; ds2 += d * d;
                    float fa = rp - rm; rh[k] -= AF * fa; rh[k + 1] += AF * fa;
                    if (k >= 1) {
                        float jo = AF * (ao - aop), jn = AF * (an - anp);
                        rp = fmaxf(jn - JMAX, 0.f); rm = fmaxf(-jn - JMAX, 0.f);
                        res2 += rp * rp + rm * rm;
                        so = fmaxf(JMAX - jo, 0.f); sn = fmaxf(JMAX - jn, 0.f);
                        d = so - sn; ds2 += d * d;
                        so = fmaxf(JMAX + jo, 0.f); sn = fmaxf(JMAX + jn, 0.f);
                        d = so - sn; ds2 += d * d;
                        float fj = rp - rm;
                        rh[k - 1] += JF * fj; rh[k] -= 2.f * JF * fj; rh[k + 1] += JF * fj;
                    }
                    aop = ao; anp = an;
                }
                xoc = xon; xnc = xnn;
            }
            float SF = TF * SpF;
#pragma unroll
            for (int k = 0; k < 50; ++k) {
                float gk = rh[k] + SF;
                dlam2 += gk * gk;
                sLam[IDX2(k)] -= gk;   // pair writes same value -> benign
            }
        }
        prs += sqrtf(res2);
        fps += sqrtf(dxi2) + sqrtf(dlam2) + sqrtf(ds2);
        float* tp = cx; cx = cn; cn = tp;
    }
#pragma unroll 1
    for (int idx = lane; idx < 1600; idx += 64) {
        int rr = idx / 50, kk = idx - rr * 50;
        out[(size_t)(base + rr) * 50 + kk] = cx[(kk << 5) + rr];
    }
    out[(size_t)BATCH * 50 + row] = fps * (1.f / 15.f);
    out[(size_t)BATCH * 51 + row] = prs * (1.f / 15.f);
#undef IDX2
}

// ---------------------------------------------------------------------------
extern "C" void kernel_launch(void* const* d_in, const int* in_sizes, int n_in,
                              void* d_out, int out_size, void* d_ws, size_t ws_size,
                              hipStream_t stream)
{
    const float* x   = (const float*)d_in[0];
    const float* W1  = (const float*)d_in[1];
    const float* b1  = (const float*)d_in[2];
    const float* g1  = (const float*)d_in[3];
    const float* be1 = (const float*)d_in[4];
    const float* W2  = (const float*)d_in[5];
    const float* b2  = (const float*)d_in[6];
    const float* g2  = (const float*)d_in[7];
    const float* be2 = (const float*)d_in[8];
    const float* W3  = (const float*)d_in[9];
    const float* b3  = (const float*)d_in[10];
    const float* g3  = (const float*)d_in[11];
    const float* be3 = (const float*)d_in[12];
    const float* W4  = (const float*)d_in[13];
    const float* b4  = (const float*)d_in[14];

    float *z1, *z2, *xp, *ps, *pq, *scb, *shb, *Mp, *xT, *nnT;
    ushort_t *w1p, *w2p, *w3p;
    hipGetSymbolAddress((void**)&z1,  HIP_SYMBOL(g_z1));
    hipGetSymbolAddress((void**)&z2,  HIP_SYMBOL(g_z2));
    hipGetSymbolAddress((void**)&xp,  HIP_SYMBOL(g_xpad));
    hipGetSymbolAddress((void**)&ps,  HIP_SYMBOL(g_ps));
    hipGetSymbolAddress((void**)&pq,  HIP_SYMBOL(g_pq));
    hipGetSymbolAddress((void**)&scb, HIP_SYMBOL(g_scale));
    hipGetSymbolAddress((void**)&shb, HIP_SYMBOL(g_shift));
    hipGetSymbolAddress((void**)&Mp,  HIP_SYMBOL(g_Mp));
    hipGetSymbolAddress((void**)&xT,  HIP_SYMBOL(g_xT));
    hipGetSymbolAddress((void**)&nnT, HIP_SYMBOL(g_nnT));
    hipGetSymbolAddress((void**)&w1p, HIP_SYMBOL(g_w1p));
    hipGetSymbolAddress((void**)&w2p, HIP_SYMBOL(g_w2p));
    hipGetSymbolAddress((void**)&w3p, HIP_SYMBOL(g_w3p));

    float* z3  = z1;                        // z1 dead after GEMM2
    float* nno = z1 + (size_t)BATCH * H3;   // after z3
    float* sc1 = scb;        float* sh1 = shb;
    float* sc2 = scb + 1024; float* sh2 = shb + 1024;
    float* sc3 = scb + 2048; float* sh3 = shb + 2048;

    dim3 blk(256);
    hipLaunchKernelGGL(build_M, dim3(1), dim3(64), 0, stream, Mp);
    hipLaunchKernelGGL(wsplit_pack, dim3(H1 / 16, 64 / 32), dim3(512), 0, stream, W1, w1p, 64, H1, NVARS);
    hipLaunchKernelGGL(wsplit_pack, dim3(H2 / 16, H1 / 32), dim3(512), 0, stream, W2, w2p, H1, H2, H1);
    hipLaunchKernelGGL(wsplit_pack, dim3(H3 / 16, H2 / 32), dim3(512), 0, stream, W3, w3p, H2, H3, H2);
    hipLaunchKernelGGL(xpad_k, dim3(2048), blk, 0, stream, x, xp);
    hipLaunchKernelGGL((transp<50>), dim3(BATCH / 64), dim3(64), 0, stream, x, xT);

    // L1: z1 = xpad @ W1 + b1 (MFMA pipelined + W-prefetch, no BN)
    hipLaunchKernelGGL((gemm_mfma<0>), dim3((BATCH / 64) * (H1 / 256)), blk, 0, stream,
                       xp, w1p, b1, (const float*)nullptr, (const float*)nullptr,
                       z1, BATCH, 64, H1, H1 / 256);
    hipLaunchKernelGGL(stats_part, dim3(H1 / 64, 32), blk, 0, stream, z1, ps, pq, BATCH, H1, 32);
    hipLaunchKernelGGL(stats_fin, dim3(4), dim3(256), 0, stream, ps, pq, g1, be1, sc1, sh1, H1, BATCH, 32);
    // L2: z2 = relu(bn(z1)) @ W2 + b2 (MFMA pipelined + W-prefetch)
    hipLaunchKernelGGL((gemm_mfma<1>), dim3((BATCH / 64) * (H2 / 256)), blk, 0, stream,
                       z1, w2p, b2, sc1, sh1, z2, BATCH, H1, H2, H2 / 256);
    hipLaunchKernelGGL(stats_part, dim3(H2 / 64, 32), blk, 0, stream, z2, ps, pq, BATCH, H2, 32);
    hipLaunchKernelGGL(stats_fin, dim3(4), dim3(256), 0, stream, ps, pq, g2, be2, sc2, sh2, H2, BATCH, 32);
    // L3: z3 = relu(bn(z2)) @ W3 + b3 (MFMA pipelined + W-prefetch)
    hipLaunchKernelGGL((gemm_mfma<1>), dim3((BATCH / 64) * (H3 / 256)), blk, 0, stream,
                       z2, w3p, b3, sc2, sh2, z3, BATCH, H2, H3, H3 / 256);
    hipLaunchKernelGGL(stats_part, dim3(H3 / 64, 32), blk, 0, stream, z3, ps, pq, BATCH, H3, 32);
    hipLaunchKernelGGL(stats_fin, dim3(1), dim3(256), 0, stream, ps, pq, g3, be3, sc3, sh3, H3, BATCH, 32);
    // L4: nno = relu(bn(z3)) @ W4 + b4 (fp32 vector path, N=100)
    hipLaunchKernelGGL((gemm_k<1>), dim3(BATCH / 128, 1), blk, 0, stream,
                       z3, W4, b4, sc3, sh3, nno, BATCH, H3, NOUT);
    hipLaunchKernelGGL((transp<100>), dim3(BATCH / 64), dim3(64), 0, stream, nno, nnT);
    // fused ADMM iterations (2 lanes/row)
    hipLaunchKernelGGL(iter_k, dim3(BATCH / 32), dim3(64), 0, stream,
                       xT, nnT, Mp, (float*)d_out);
}

// Round 18
// 1435.321 us; speedup vs baseline: 1.1772x; 1.1772x over previous
//
#include <hip/hip_runtime.h>
#include <math.h>

#define BATCH 32768
#define NVARS 50
#define H1 1024
#define H2 1024
#define H3 256
#define NOUT 100
#define EPSBN 1e-5f

#define TF   0.05f
#define AF   20.0f
#define JF   400.0f
#define VMAX 1.0f
#define AMAX 2.0f
#define JMAX 5.0f
#define PMAX 3.14159265358979323846f

typedef unsigned short ushort_t;
typedef __attribute__((ext_vector_type(8))) short short8;
typedef __attribute__((ext_vector_type(4))) float f32x4;

// ---------------------------------------------------------------------------
// Device-global scratch (no ws_size dependence).
// ---------------------------------------------------------------------------
__device__ float g_z1[(size_t)BATCH * H1];   // z1 / (z3, nno reuse)
__device__ float g_z2[(size_t)BATCH * H2];
__device__ float g_xpad[(size_t)BATCH * 64]; // x zero-padded K=50 -> 64
__device__ float g_ps[32 * 1024];
__device__ float g_pq[32 * 1024];
__device__ float g_scale[3 * 1024];
__device__ float g_shift[3 * 1024];
__device__ float g_Mp[2800];                 // Qinv packed [k][par][28] (pad 0)
__device__ float g_xT[(size_t)NVARS * BATCH];
__device__ float g_nnT[(size_t)NOUT * BATCH];
__device__ ushort_t g_w1p[(size_t)3 * 64 * H1];   // packed W1 (K padded to 64)
__device__ ushort_t g_w2p[(size_t)3 * H1 * H2];   // packed fragment-order tiers
__device__ ushort_t g_w3p[(size_t)3 * H2 * H3];

// ---------------------------------------------------------------------------
// float -> bf16 triple split (RNE), f ~= hi + mid + lo with rel err ~2^-26.
// ---------------------------------------------------------------------------
__device__ __forceinline__ void split3(float f, ushort_t& h, ushort_t& m, ushort_t& l)
{
    unsigned u = __float_as_uint(f);
    unsigned r = u + 0x7fffu + ((u >> 16) & 1u);
    h = (ushort_t)(r >> 16);
    float f1 = f - __uint_as_float((unsigned)h << 16);
    unsigned u1 = __float_as_uint(f1);
    unsigned r1 = u1 + 0x7fffu + ((u1 >> 16) & 1u);
    m = (ushort_t)(r1 >> 16);
    float f2 = f1 - __uint_as_float((unsigned)m << 16);
    unsigned u2 = __float_as_uint(f2);
    unsigned r2 = u2 + 0x7fffu + ((u2 >> 16) & 1u);
    l = (ushort_t)(r2 >> 16);
}

// ---------------------------------------------------------------------------
// Build Mp[(k*2+par)*28 + jj] = Q_inv[par*25+jj][k] (jj<25; pad 0) via f64
// Gauss-Jordan with partial pivoting (bitwise-identical values).
// ---------------------------------------------------------------------------
__global__ void build_M(float* __restrict__ Mout)
{
    __shared__ double aug[52][104];
    __shared__ int piv;
    int tid = threadIdx.x;

    const double Tf = (double)0.05f;
    const double c3[3] = { 400.0, -800.0, 400.0 };

    for (int idx = tid; idx < 52 * 104; idx += 64) {
        int j = idx / 104, k = idx % 104;
        double v = 0.0;
        if (k >= 52) {
            v = (k == 52 + j) ? 1.0 : 0.0;
        } else if (j < 50 && k < 50) {
            double q = (j == k) ? 3.0 : 0.0;
            if (j == k) q += 800.0 * ((j < 49 ? 1 : 0) + (j > 0 ? 1 : 0));
            if (j - k == 1 || k - j == 1) q += -800.0;
            int lo = j > k ? j : k; lo -= 2; if (lo < 0) lo = 0;
            int hi = j < k ? j : k; if (hi > 47) hi = 47;
            for (int i = lo; i <= hi; ++i) {
                int dj = j - i, dk = k - i;
                if (dj >= 0 && dj <= 2 && dk >= 0 && dk <= 2)
                    q += 2.0 * c3[dj] * c3[dk];
            }
            int mx = j > k ? j : k;
            q += 2.0 * Tf * Tf * (double)(50 - mx);
            v = q;
        } else if ((j == 50 && k == 0) || (j == 0 && k == 50) ||
                   (j == 51 && k == 49) || (j == 49 && k == 51)) {
            v = 1.0;
        }
        aug[j][k] = v;
    }
    __syncthreads();

    for (int c = 0; c < 52; ++c) {
        if (tid == 0) {
            int p = c; double best = fabs(aug[c][c]);
            for (int r = c + 1; r < 52; ++r) {
                double v = fabs(aug[r][c]);
                if (v > best) { best = v; p = r; }
            }
            piv = p;
        }
        __syncthreads();
        int p = piv;
        if (p != c) {
            for (int k = tid; k < 104; k += 64) {
                double t = aug[c][k]; aug[c][k] = aug[p][k]; aug[p][k] = t;
            }
        }
        __syncthreads();
        double pv = aug[c][c];
        __syncthreads();
        for (int k = tid; k < 104; k += 64) aug[c][k] /= pv;
        __syncthreads();
        if (tid < 52 && tid != c) {
            double f = aug[tid][c];
            for (int k = 0; k < 104; ++k) aug[tid][k] -= f * aug[c][k];
        }
        __syncthreads();
    }

    // Mp[(k*2+par)*28 + slot] = Qinv[par*25+slot][k]  (slot 25..27 -> 0)
    for (int idx = tid; idx < 2800; idx += 64) {
        int slot = idx % 28;
        int kk2 = idx / 28;
        int k = kk2 >> 1, par = kk2 & 1;
        int j = par * 25 + slot;
        Mout[idx] = (slot < 25) ? (float)aug[j][52 + k] : 0.f;
    }
}

// ---------------------------------------------------------------------------
// Pad x[BATCH][50] -> xpad[BATCH][64] (zeros beyond col 50).
// ---------------------------------------------------------------------------
__global__ __launch_bounds__(256)
void xpad_k(const float* __restrict__ X, float* __restrict__ XP)
{
    size_t idx = (size_t)blockIdx.x * 256 + threadIdx.x;
    size_t total = (size_t)BATCH * 64;
    for (; idx < total; idx += (size_t)gridDim.x * 256) {
        int col = (int)(idx & 63);
        size_t row = idx >> 6;
        XP[idx] = (col < NVARS) ? X[row * NVARS + col] : 0.f;
    }
}

// ---------------------------------------------------------------------------
// Transpose Z[BATCH][C] -> ZT[C][BATCH], 64 rows per block.
// ---------------------------------------------------------------------------
template <int C>
__global__ __launch_bounds__(64)
void transp(const float* __restrict__ Z, float* __restrict__ ZT)
{
    __shared__ float t[64][C + 1];
    const int lane = threadIdx.x;
    const size_t r0 = (size_t)blockIdx.x * 64;
#pragma unroll 1
    for (int i = 0; i < C; ++i) {
        int idx = i * 64 + lane;
        int r = idx / C, c = idx % C;
        t[r][c] = Z[r0 * C + idx];
    }
    __syncthreads();
#pragma unroll 1
    for (int c = 0; c < C; ++c)
        ZT[(size_t)c * BATCH + r0 + lane] = t[lane][c];
}

// ---------------------------------------------------------------------------
// Triple-split W[Kr][N] f32 -> Wp packed in MFMA-fragment order, K padded
// to multiple of 32 (rows >= Kr are zeros).
// ---------------------------------------------------------------------------
__global__ __launch_bounds__(512)
void wsplit_pack(const float* __restrict__ W, ushort_t* __restrict__ Wp,
                 int K, int N, int Kr)
{
    int t = threadIdx.x;
    int n0 = blockIdx.x * 16, k0 = blockIdx.y * 32;
    int kk = t >> 4, nn = t & 15;
    float f = (k0 + kk < Kr) ? W[(size_t)(k0 + kk) * N + n0 + nn] : 0.f;
    ushort_t h, m, l;
    split3(f, h, m, l);
    int Nsub = N >> 4;
    int lane = (kk >> 3) * 16 + nn, e = kk & 7;
    size_t base = ((size_t)((k0 >> 5) * Nsub + (n0 >> 4)) * 3) * 512 + lane * 8 + e;
    Wp[base]        = h;
    Wp[base + 512]  = m;
    Wp[base + 1024] = l;
}

// ---------------------------------------------------------------------------
// MFMA GEMM (pipelined): BM=64/BN=256, dbuf 24KB LDS (A only), one barrier
// per K-step, early A prefetch, packed-global W, XCD swizzle. BN_APPLY=0
// skips BN/relu (L1). Best-measured configuration (R15: 1441 us total).
// ---------------------------------------------------------------------------
template <int BN_APPLY>
__global__ __launch_bounds__(256)
void gemm_mfma(const float* __restrict__ A, const ushort_t* __restrict__ Wp,
               const float* __restrict__ bias,
               const float* __restrict__ scale, const float* __restrict__ shift,
               float* __restrict__ C, int M, int K, int N, int ntn)
{
    __shared__ __attribute__((aligned(16))) ushort_t lds[2][3][4][64][8];  // 24 KB

    const int nwg = gridDim.x;
    const int chunk = nwg >> 3;
    const int b = blockIdx.x;
    const int logical = (b & 7) * chunk + (b >> 3);
    const int rowt = logical / ntn;
    const int colt = logical - rowt * ntn;
    const int row0 = rowt * 64;
    const int col0s = colt * 16;

    const int t = threadIdx.x;
    const int lane = t & 63, wn = t >> 6;
    const int fr = lane & 15, fg = lane >> 4;
    const int srow = t & 63, skc = t >> 6;
    const int Nsub = N >> 4;
    const int nk = K >> 5;

    f32x4 acc[4][4];
#pragma unroll
    for (int m = 0; m < 4; ++m)
#pragma unroll
        for (int n = 0; n < 4; ++n)
#pragma unroll
            for (int q = 0; q < 4; ++q) acc[m][n][q] = 0.f;

    const float* arow = A + (size_t)(row0 + srow) * K + skc * 8;

#define SPLIT_WRITE(BUF, F0, F1, KOFF)                                         \
    {                                                                          \
        float v[8];                                                            \
        v[0] = (F0).x; v[1] = (F0).y; v[2] = (F0).z; v[3] = (F0).w;            \
        v[4] = (F1).x; v[5] = (F1).y; v[6] = (F1).z; v[7] = (F1).w;            \
        if (BN_APPLY) {                                                        \
            const float* scp = scale + (KOFF) + skc * 8;                       \
            const float* shp = shift + (KOFF) + skc * 8;                       \
            float4 sc0 = *(const float4*)scp, sc1 = *(const float4*)(scp + 4); \
            float4 sh0 = *(const float4*)shp, sh1 = *(const float4*)(shp + 4); \
            v[0] = fmaxf(v[0] * sc0.x + sh0.x, 0.f);                           \
            v[1] = fmaxf(v[1] * sc0.y + sh0.y, 0.f);                           \
            v[2] = fmaxf(v[2] * sc0.z + sh0.z, 0.f);                           \
            v[3] = fmaxf(v[3] * sc0.w + sh0.w, 0.f);                           \
            v[4] = fmaxf(v[4] * sc1.x + sh1.x, 0.f);                           \
            v[5] = fmaxf(v[5] * sc1.y + sh1.y, 0.f);                           \
            v[6] = fmaxf(v[6] * sc1.z + sh1.z, 0.f);                           \
            v[7] = fmaxf(v[7] * sc1.w + sh1.w, 0.f);                           \
        }                                                                      \
        ushort_t h_[8], m_[8], l_[8];                                          \
        _Pragma("unroll")                                                      \
        for (int q = 0; q < 8; ++q) split3(v[q], h_[q], m_[q], l_[q]);         \
        *(uint4*)&lds[BUF][0][skc][srow][0] = make_uint4(                      \
            (unsigned)h_[0] | ((unsigned)h_[1] << 16),                         \
            (unsigned)h_[2] | ((unsigned)h_[3] << 16),                         \
            (unsigned)h_[4] | ((unsigned)h_[5] << 16),                         \
            (unsigned)h_[6] | ((unsigned)h_[7] << 16));                        \
        *(uint4*)&lds[BUF][1][skc][srow][0] = make_uint4(                      \
            (unsigned)m_[0] | ((unsigned)m_[1] << 16),                         \
            (unsigned)m_[2] | ((unsigned)m_[3] << 16),                         \
            (unsigned)m_[4] | ((unsigned)m_[5] << 16),                         \
            (unsigned)m_[6] | ((unsigned)m_[7] << 16));                        \
        *(uint4*)&lds[BUF][2][skc][srow][0] = make_uint4(                      \
            (unsigned)l_[0] | ((unsigned)l_[1] << 16),                         \
            (unsigned)l_[2] | ((unsigned)l_[3] << 16),                         \
            (unsigned)l_[4] | ((unsigned)l_[5] << 16),                         \
            (unsigned)l_[6] | ((unsigned)l_[7] << 16));                        \
    }

    {
        float4 f0 = *(const float4*)(arow);
        float4 f1 = *(const float4*)(arow + 4);
        SPLIT_WRITE(0, f0, f1, 0)
    }
    __syncthreads();

    int cur = 0;
    for (int ks = 0; ks < nk; ++ks) {
        int kn = (ks + 1 < nk) ? (ks + 1) : ks;
        float4 f0 = *(const float4*)(arow + kn * 32);
        float4 f1 = *(const float4*)(arow + kn * 32 + 4);

        short8 b_h[4], b_m[4], b_l[4];
#pragma unroll
        for (int n = 0; n < 4; ++n) {
            size_t base = ((size_t)(ks * Nsub + col0s + wn * 4 + n) * 3) * 512 + lane * 8;
            b_h[n] = *(const short8*)(Wp + base);
            b_m[n] = *(const short8*)(Wp + base + 512);
            b_l[n] = *(const short8*)(Wp + base + 1024);
        }
#pragma unroll
        for (int m = 0; m < 4; ++m) {
            int r = m * 16 + fr;
            short8 a_h = *(const short8*)&lds[cur][0][fg][r][0];
            short8 a_m = *(const short8*)&lds[cur][1][fg][r][0];
            short8 a_l = *(const short8*)&lds[cur][2][fg][r][0];
#pragma unroll
            for (int n = 0; n < 4; ++n) {
                f32x4 c = acc[m][n];
                c = __builtin_amdgcn_mfma_f32_16x16x32_bf16(a_l, b_h[n], c, 0, 0, 0);
                c = __builtin_amdgcn_mfma_f32_16x16x32_bf16(a_h, b_l[n], c, 0, 0, 0);
                c = __builtin_amdgcn_mfma_f32_16x16x32_bf16(a_m, b_m[n], c, 0, 0, 0);
                c = __builtin_amdgcn_mfma_f32_16x16x32_bf16(a_m, b_h[n], c, 0, 0, 0);
                c = __builtin_amdgcn_mfma_f32_16x16x32_bf16(a_h, b_m[n], c, 0, 0, 0);
                c = __builtin_amdgcn_mfma_f32_16x16x32_bf16(a_h, b_h[n], c, 0, 0, 0);
                acc[m][n] = c;
            }
        }
        if (ks + 1 < nk) {
            SPLIT_WRITE(cur ^ 1, f0, f1, (ks + 1) * 32)
        }
        __syncthreads();
        cur ^= 1;
    }
#undef SPLIT_WRITE

#pragma unroll
    for (int m = 0; m < 4; ++m)
#pragma unroll
        for (int n = 0; n < 4; ++n) {
            int cc = (col0s + wn * 4 + n) * 16 + fr;
            float bv = bias[cc];
#pragma unroll
            for (int q = 0; q < 4; ++q) {
                int rr = row0 + m * 16 + fg * 4 + q;
                C[(size_t)rr * N + cc] = acc[m][n][q] + bv;
            }
        }
}

// ---------------------------------------------------------------------------
// fp32 tiled GEMM (GEMM4 N=100 only).
// ---------------------------------------------------------------------------
template <int BN_APPLY>
__global__ __launch_bounds__(256)
void gemm_k(const float* __restrict__ A, const float* __restrict__ W,
            const float* __restrict__ bias,
            const float* __restrict__ scale, const float* __restrict__ shift,
            float* __restrict__ C, int M, int K, int N)
{
    const int BM = 128, BN = 128, BK = 16;
    __shared__ __attribute__((aligned(16))) float As[BK][BM + 4];
    __shared__ __attribute__((aligned(16))) float Ws[BK][BN];
    int tid = threadIdx.x;
    int tm = tid >> 4, tn = tid & 15;
    int row0 = blockIdx.x * BM, col0 = blockIdx.y * BN;

    float acc[8][8];
#pragma unroll
    for (int i = 0; i < 8; ++i)
#pragma unroll
        for (int j = 0; j < 8; ++j) acc[i][j] = 0.f;

    int alr = tid >> 4;
    int alk = tid & 15;
    int wlc = tid & 127;
    int wlk = tid >> 7;

    for (int k0 = 0; k0 < K; k0 += BK) {
#pragma unroll
        for (int i = 0; i < 8; ++i) {
            int rr = row0 + alr + i * 16;
            int kk = k0 + alk;
            float v = 0.f;
            if (kk < K) {
                v = A[(size_t)rr * K + kk];
                if (BN_APPLY) v = fmaxf(v * scale[kk] + shift[kk], 0.f);
            }
            As[alk][alr + i * 16] = v;
        }
#pragma unroll
        for (int i = 0; i < 8; ++i) {
            int kk = k0 + wlk + i * 2;
            int cc = col0 + wlc;
            Ws[wlk + i * 2][wlc] = (kk < K && cc < N) ? W[(size_t)kk * N + cc] : 0.f;
        }
        __syncthreads();
#pragma unroll
        for (int kk = 0; kk < BK; ++kk) {
            float av[8], wv[8];
            float4 tv;
            tv = *(const float4*)&As[kk][tm * 8];     av[0]=tv.x; av[1]=tv.y; av[2]=tv.z; av[3]=tv.w;
            tv = *(const float4*)&As[kk][tm * 8 + 4]; av[4]=tv.x; av[5]=tv.y; av[6]=tv.z; av[7]=tv.w;
            tv = *(const float4*)&Ws[kk][tn * 8];     wv[0]=tv.x; wv[1]=tv.y; wv[2]=tv.z; wv[3]=tv.w;
            tv = *(const float4*)&Ws[kk][tn * 8 + 4]; wv[4]=tv.x; wv[5]=tv.y; wv[6]=tv.z; wv[7]=tv.w;
#pragma unroll
            for (int i = 0; i < 8; ++i)
#pragma unroll
                for (int j = 0; j < 8; ++j) acc[i][j] += av[i] * wv[j];
        }
        __syncthreads();
    }
#pragma unroll
    for (int i = 0; i < 8; ++i) {
        int rr = row0 + tm * 8 + i;
#pragma unroll
        for (int j = 0; j < 8; ++j) {
            int cc = col0 + tn * 8 + j;
            if (cc < N) C[(size_t)rr * N + cc] = acc[i][j] + bias[cc];
        }
    }
}

// ---------------------------------------------------------------------------
// BatchNorm stats.
// ---------------------------------------------------------------------------
__global__ __launch_bounds__(256)
void stats_part(const float* __restrict__ Z, float* __restrict__ ps,
                float* __restrict__ pq, int M, int C, int chunks)
{
    int lc = threadIdx.x & 63;
    int col = blockIdx.x * 64 + lc;
    int rg = threadIdx.x >> 6;
    int rpc = M / chunks;
    int r0 = blockIdx.y * rpc;
    float s = 0.f, q = 0.f;
    for (int rr = r0 + rg; rr < r0 + rpc; rr += 4) {
        float v = Z[(size_t)rr * C + col];
        s += v; q += v * v;
    }
    __shared__ float ls[4][64], lq[4][64];
    ls[rg][lc] = s; lq[rg][lc] = q;
    __syncthreads();
    if (rg == 0) {
        float S = ls[0][lc] + ls[1][lc] + ls[2][lc] + ls[3][lc];
        float Q = lq[0][lc] + lq[1][lc] + lq[2][lc] + lq[3][lc];
        ps[(size_t)blockIdx.y * C + col] = S;
        pq[(size_t)blockIdx.y * C + col] = Q;
    }
}

__global__ void stats_fin(const float* __restrict__ ps, const float* __restrict__ pq,
                          const float* __restrict__ g, const float* __restrict__ be,
                          float* __restrict__ scale, float* __restrict__ shift,
                          int C, int M, int chunks)
{
    int c = blockIdx.x * blockDim.x + threadIdx.x;
    if (c >= C) return;
    float S = 0.f, Q = 0.f;
    for (int i = 0; i < chunks; ++i) { S += ps[(size_t)i * C + c]; Q += pq[(size_t)i * C + c]; }
    float inv = 1.0f / (float)M;
    float mean = S * inv;
    float var = Q * inv - mean * mean;
    float rstd = 1.0f / sqrtf(var + EPSBN);
    float sc = g[c] * rstd;
    scale[c] = sc;
    shift[c] = be[c] - mean * sc;
}

// ---------------------------------------------------------------------------
// Fused 15-iteration ADMM, 2 lanes/row (grid-capped at 1 wave/SIMD;
// known-good at ~370 us, VGPR 92, no spill).
// ---------------------------------------------------------------------------
__global__ __launch_bounds__(64, 1)
void iter_k(const float* __restrict__ XT, const float* __restrict__ NNT,
            const float* __restrict__ Mp, float* __restrict__ out)
{
    __shared__ float sA[50 * 32];
    __shared__ float sB[50 * 32];
    __shared__ float sLam[50 * 32];
    __shared__ float sRh[50 * 32];
    const int lane = threadIdx.x;
    const int r = lane >> 1, par = lane & 1;
    const int base = blockIdx.x * 32;
    const int row = base + r;
#define IDX2(k) (((k) << 5) + r)

#pragma unroll 1
    for (int idx = lane; idx < 1600; idx += 64) {
        int k = idx >> 5, rr = idx & 31;
        sA[idx]   = NNT[(size_t)k * BATCH + base + rr];
        sLam[idx] = NNT[(size_t)(50 + k) * BATCH + base + rr];
    }
    float* cx = sA;
    float* cn = sB;
    float fps = 0.f, prs = 0.f;
    float rh[50];
    const float* mp = Mp + par * 28;

#pragma unroll 1
    for (int it = 0; it < 15; ++it) {
        // ---- pass 1: rh = A^T min(b, A xi); xi via sliding LDS reads
#pragma unroll
        for (int k = 0; k < 50; ++k) rh[k] = 0.f;
        {
            float pre = 0.f, Sp = 0.f, ap = 0.f;
            float xc = cx[IDX2(0)];
#pragma unroll
            for (int k = 0; k < 50; ++k) {
                float xn = (k < 49) ? cx[IDX2(k + 1)] : 0.f;
                rh[k] += fminf(VMAX, xc) - fminf(VMAX, -xc);
                rh[k] -= TF * Sp;
                pre += xc;
                float p = TF * pre;
                Sp += fminf(PMAX, p) - fminf(PMAX, -p);
                if (k < 49) {
                    float a = AF * (xn - xc);
                    float da = fminf(AMAX, a) - fminf(AMAX, -a);
                    rh[k] -= AF * da; rh[k + 1] += AF * da;
                    if (k >= 1) {
                        float j = AF * (a - ap);
                        float dj = fminf(JMAX, j) - fminf(JMAX, -j);
                        rh[k - 1] += JF * dj; rh[k] -= 2.f * JF * dj; rh[k + 1] += JF * dj;
                    }
                    ap = a;
                }
                xc = xn;
            }
            float Stot = TF * Sp;
            // combine: + lam (LDS) + x (global, L2-resident) + Stot -> sRh
#pragma unroll
            for (int k = 0; k < 50; ++k)
                sRh[IDX2(k)] = rh[k] + sLam[IDX2(k)] + XT[(size_t)k * BATCH + row] + Stot;
        }

        // ---- matvec half: xin[par*25+jj] = sum_k Mp[(2k+par)*28+jj]*sRh[k]
        {
            float xr[28];
#pragma unroll
            for (int jj = 0; jj < 28; ++jj) xr[jj] = 0.f;
#pragma unroll 2
            for (int k = 0; k < 50; ++k) {
                float rv = sRh[IDX2(k)];
                const float4* m4 = (const float4*)(mp + k * 56);
#pragma unroll
                for (int p4 = 0; p4 < 7; ++p4) {
                    float4 mv = m4[p4];
                    xr[p4 * 4 + 0] += mv.x * rv;
                    xr[p4 * 4 + 1] += mv.y * rv;
                    xr[p4 * 4 + 2] += mv.z * rv;
                    xr[p4 * 4 + 3] += mv.w * rv;
                }
            }
#pragma unroll
            for (int jj = 0; jj < 25; ++jj)
                cn[((par * 25 + jj) << 5) + r] = xr[jj];
        }

        // ---- pass 2: residual/s norms + g (into rh); duplicated per pair
        float res2 = 0.f, ds2 = 0.f, dxi2 = 0.f, dlam2 = 0.f;
#pragma unroll
        for (int k = 0; k < 50; ++k) rh[k] = 0.f;
        {
            float preo = 0.f, pren = 0.f, SpF = 0.f, aop = 0.f, anp = 0.f;
            float xoc = cx[IDX2(0)], xnc = cn[IDX2(0)];
#pragma unroll
            for (int k = 0; k < 50; ++k) {
                float xon = (k < 49) ? cx[IDX2(k + 1)] : 0.f;
                float xnn = (k < 49) ? cn[IDX2(k + 1)] : 0.f;
                float d = xoc - xnc; dxi2 += d * d;
                float rp = fmaxf(xnc - VMAX, 0.f), rm = fmaxf(-xnc - VMAX, 0.f);
                res2 += rp * rp + rm * rm;
                float so = fmaxf(VMAX - xoc, 0.f), sn = fmaxf(VMAX - xnc, 0.f);
                d = so - sn; ds2 += d * d;
                so = fmaxf(VMAX + xoc, 0.f); sn = fmaxf(VMAX + xnc, 0.f);
                d = so - sn; ds2 += d * d;
                rh[k] += rp - rm;
                rh[k] -= TF * SpF;
                preo += xoc; pren += xnc;
                float po = TF * preo, pn = TF * pren;
                rp = fmaxf(pn - PMAX, 0.f); rm = fmaxf(-pn - PMAX, 0.f);
                res2 += rp * rp + rm * rm;
                so = fmaxf(PMAX - po, 0.f); sn = fmaxf(PMAX - pn, 0.f);
                d = so - sn; ds2 += d * d;
                so = fmaxf(PMAX + po, 0.f); sn = fmaxf(PMAX + pn, 0.f);
                d = so - sn; ds2 += d * d;
                SpF += rp - rm;
                if (k < 49) {
                    float ao = AF * (xon - xoc), an = AF * (xnn - xnc);
                    rp = fmaxf(an - AMAX, 0.f); rm = fmaxf(-an - AMAX, 0.f);
                    res2 += rp * rp + rm * rm;
                    so = fmaxf(AMAX - ao, 0.f); sn = fmaxf(AMAX - an, 0.f);
                    d = so - sn; ds2 += d * d;
                    so = fmaxf(AMAX + ao, 0.f); sn = fmaxf(AMAX + an, 0.f);
                    d = so - sn; ds2 += d * d;
                    float fa = rp - rm; rh[k] -= AF * fa; rh[k + 1] += AF * fa;
                    if (k >= 1) {
                        float jo = AF * (ao - aop), jn = AF * (an - anp);
                        rp = fmaxf(jn - JMAX, 0.f); rm = fmaxf(-jn - JMAX, 0.f);
                        res2 += rp * rp + rm * rm;
                        so = fmaxf(JMAX - jo, 0.f); sn = fmaxf(JMAX - jn, 0.f);
                        d = so - sn; ds2 += d * d;
                        so = fmaxf(JMAX + jo, 0.f); sn = fmaxf(JMAX + jn, 0.f);
                        d = so - sn; ds2 += d * d;
                        float fj = rp - rm;
                        rh[k - 1] += JF * fj; rh[k] -= 2.f * JF * fj; rh[k + 1] += JF * fj;
                    }
                    aop = ao; anp = an;
                }
                xoc = xon; xnc = xnn;
            }
            float SF = TF * SpF;
#pragma unroll
            for (int k = 0; k < 50; ++k) {
                float gk = rh[k] + SF;
                dlam2 += gk * gk;
                sLam[IDX2(k)] -= gk;   // pair writes same value -> benign
            }
        }
        prs += sqrtf(res2);
        fps += sqrtf(dxi2) + sqrtf(dlam2) + sqrtf(ds2);
        float* tp = cx; cx = cn; cn = tp;
    }
#pragma unroll 1
    for (int idx = lane; idx < 1600; idx += 64) {
        int rr = idx / 50, kk = idx - rr * 50;
        out[(size_t)(base + rr) * 50 + kk] = cx[(kk << 5) + rr];
    }
    out[(size_t)BATCH * 50 + row] = fps * (1.f / 15.f);
    out[(size_t)BATCH * 51 + row] = prs * (1.f / 15.f);
#undef IDX2
}

// ---------------------------------------------------------------------------
extern "C" void kernel_launch(void* const* d_in, const int* in_sizes, int n_in,
                              void* d_out, int out_size, void* d_ws, size_t ws_size,
                              hipStream_t stream)
{
    const float* x   = (const float*)d_in[0];
    const float* W1  = (const float*)d_in[1];
    const float* b1  = (const float*)d_in[2];
    const float* g1  = (const float*)d_in[3];
    const float* be1 = (const float*)d_in[4];
    const float* W2  = (const float*)d_in[5];
    const float* b2  = (const float*)d_in[6];
    const float* g2  = (const float*)d_in[7];
    const float* be2 = (const float*)d_in[8];
    const float* W3  = (const float*)d_in[9];
    const float* b3  = (const float*)d_in[10];
    const float* g3  = (const float*)d_in[11];
    const float* be3 = (const float*)d_in[12];
    const float* W4  = (const float*)d_in[13];
    const float* b4  = (const float*)d_in[14];

    float *z1, *z2, *xp, *ps, *pq, *scb, *shb, *Mp, *xT, *nnT;
    ushort_t *w1p, *w2p, *w3p;
    hipGetSymbolAddress((void**)&z1,  HIP_SYMBOL(g_z1));
    hipGetSymbolAddress((void**)&z2,  HIP_SYMBOL(g_z2));
    hipGetSymbolAddress((void**)&xp,  HIP_SYMBOL(g_xpad));
    hipGetSymbolAddress((void**)&ps,  HIP_SYMBOL(g_ps));
    hipGetSymbolAddress((void**)&pq,  HIP_SYMBOL(g_pq));
    hipGetSymbolAddress((void**)&scb, HIP_SYMBOL(g_scale));
    hipGetSymbolAddress((void**)&shb, HIP_SYMBOL(g_shift));
    hipGetSymbolAddress((void**)&Mp,  HIP_SYMBOL(g_Mp));
    hipGetSymbolAddress((void**)&xT,  HIP_SYMBOL(g_xT));
    hipGetSymbolAddress((void**)&nnT, HIP_SYMBOL(g_nnT));
    hipGetSymbolAddress((void**)&w1p, HIP_SYMBOL(g_w1p));
    hipGetSymbolAddress((void**)&w2p, HIP_SYMBOL(g_w2p));
    hipGetSymbolAddress((void**)&w3p, HIP_SYMBOL(g_w3p));

    float* z3  = z1;                        // z1 dead after GEMM2
    float* nno = z1 + (size_t)BATCH * H3;   // after z3
    float* sc1 = scb;        float* sh1 = shb;
    float* sc2 = scb + 1024; float* sh2 = shb + 1024;
    float* sc3 = scb + 2048; float* sh3 = shb + 2048;

    dim3 blk(256);
    hipLaunchKernelGGL(build_M, dim3(1), dim3(64), 0, stream, Mp);
    hipLaunchKernelGGL(wsplit_pack, dim3(H1 / 16, 64 / 32), dim3(512), 0, stream, W1, w1p, 64, H1, NVARS);
    hipLaunchKernelGGL(wsplit_pack, dim3(H2 / 16, H1 / 32), dim3(512), 0, stream, W2, w2p, H1, H2, H1);
    hipLaunchKernelGGL(wsplit_pack, dim3(H3 / 16, H2 / 32), dim3(512), 0, stream, W3, w3p, H2, H3, H2);
    hipLaunchKernelGGL(xpad_k, dim3(2048), blk, 0, stream, x, xp);
    hipLaunchKernelGGL((transp<50>), dim3(BATCH / 64), dim3(64), 0, stream, x, xT);

    // L1: z1 = xpad @ W1 + b1 (MFMA pipelined, no BN)
    hipLaunchKernelGGL((gemm_mfma<0>), dim3((BATCH / 64) * (H1 / 256)), blk, 0, stream,
                       xp, w1p, b1, (const float*)nullptr, (const float*)nullptr,
                       z1, BATCH, 64, H1, H1 / 256);
    hipLaunchKernelGGL(stats_part, dim3(H1 / 64, 32), blk, 0, stream, z1, ps, pq, BATCH, H1, 32);
    hipLaunchKernelGGL(stats_fin, dim3(4), dim3(256), 0, stream, ps, pq, g1, be1, sc1, sh1, H1, BATCH, 32);
    // L2: z2 = relu(bn(z1)) @ W2 + b2 (MFMA pipelined)
    hipLaunchKernelGGL((gemm_mfma<1>), dim3((BATCH / 64) * (H2 / 256)), blk, 0, stream,
                       z1, w2p, b2, sc1, sh1, z2, BATCH, H1, H2, H2 / 256);
    hipLaunchKernelGGL(stats_part, dim3(H2 / 64, 32), blk, 0, stream, z2, ps, pq, BATCH, H2, 32);
    hipLaunchKernelGGL(stats_fin, dim3(4), dim3(256), 0, stream, ps, pq, g2, be2, sc2, sh2, H2, BATCH, 32);
    // L3: z3 = relu(bn(z2)) @ W3 + b3 (MFMA pipelined)
    hipLaunchKernelGGL((gemm_mfma<1>), dim3((BATCH / 64) * (H3 / 256)), blk, 0, stream,
                       z2, w3p, b3, sc2, sh2, z3, BATCH, H2, H3, H3 / 256);
    hipLaunchKernelGGL(stats_part, dim3(H3 / 64, 32), blk, 0, stream, z3, ps, pq, BATCH, H3, 32);
    hipLaunchKernelGGL(stats_fin, dim3(1), dim3(256), 0, stream, ps, pq, g3, be3, sc3, sh3, H3, BATCH, 32);
    // L4: nno = relu(bn(z3)) @ W4 + b4 (fp32 vector path, N=100)
    hipLaunchKernelGGL((gemm_k<1>), dim3(BATCH / 128, 1), blk, 0, stream,
                       z3, W4, b4, sc3, sh3, nno, BATCH, H3, NOUT);
    hipLaunchKernelGGL((transp<100>), dim3(BATCH / 64), dim3(64), 0, stream, nno, nnT);
    // fused ADMM iterations (2 lanes/row)
    hipLaunchKernelGGL(iter_k, dim3(BATCH / 32), dim3(64), 0, stream,
                       xT, nnT, Mp, (float*)d_out);
}